// Round 10
// baseline (149.342 us; speedup 1.0000x reference)
//
#include <hip/hip_runtime.h>
#include <hip/hip_bf16.h>

// MPNN: B=8, N=36, H=64, STEPS=5
// messages[b,j,k] = (1/N^2) * sum_{i,l} edge[b,i,j,k,l] * nodes[b,i,l]
// nodes = GRUCell(messages, nodes) * mask, repeated STEPS times.
//
// Structure (6 launches):
//  K0: cvt_edge — pure streaming f32->bf16 edge conversion (170 MB R, 85 MB W),
//      memcpy-shaped: 1728 blocks x 256 threads, 32B load + 16B store per lane.
//  K1..K5: step_bf16 — fused einsum+GRU per step on the bf16 copy
//      (measured ~9 us each in round 8 when ebf is L3-resident).

#define BB 8
#define NN 36
#define HH 64
#define WAVES 4         // waves per block in fused steps
#define IPW (NN / WAVES)// 9
#define NBJ (BB * NN)   // 288
#define INVN2 (1.0f / (float)(NN * NN))
#define EDGE_U4 (((size_t)BB * NN * NN * HH * HH) / 8)   // 5,308,416 uint4 outputs

__device__ __forceinline__ unsigned bf16rtn(float f) {
    unsigned u = __float_as_uint(f);
    return (u + 0x7FFFu + ((u >> 16) & 1u)) >> 16;
}

// ---------------------------------------------------------------------------
// K0: pure streaming conversion. Thread handles uint4 output o (8 bf16) from
// 32B of f32 at edge[o*8..o*8+7]. Grid-stride, exactly 12 iters at 1728x256.
// ---------------------------------------------------------------------------
__global__ __launch_bounds__(256) void cvt_edge(
    const float* __restrict__ edge,
    uint4* __restrict__ ebf)
{
    const size_t idx0   = (size_t)blockIdx.x * 256 + threadIdx.x;
    const size_t stride = (size_t)gridDim.x * 256;
    #pragma unroll
    for (int it = 0; it < 12; ++it) {
        const size_t o = idx0 + (size_t)it * stride;
        if (o < EDGE_U4) {
            const float4 a = *(const float4*)(edge + o * 8);
            const float4 b = *(const float4*)(edge + o * 8 + 4);
            uint4 pk;
            pk.x = bf16rtn(a.x) | (bf16rtn(a.y) << 16);
            pk.y = bf16rtn(a.z) | (bf16rtn(a.w) << 16);
            pk.z = bf16rtn(b.x) | (bf16rtn(b.y) << 16);
            pk.w = bf16rtn(b.z) | (bf16rtn(b.w) << 16);
            ebf[o] = pk;
        }
    }
}

// GRU cell for one node; lane t computes output dim t from LDS-staged
// message (ms) and hidden (hs) vectors. Rows t, t+64, t+128 of w_ih/w_hh.
__device__ __forceinline__ float gru_lane(
    const float* __restrict__ ms, const float* __restrict__ hs, int t,
    const float* __restrict__ w_ih, const float* __restrict__ w_hh,
    const float* __restrict__ b_ih, const float* __restrict__ b_hh)
{
    float gi0 = b_ih[t], gi1 = b_ih[HH + t], gi2 = b_ih[2 * HH + t];
    float gh0 = b_hh[t], gh1 = b_hh[HH + t], gh2 = b_hh[2 * HH + t];

    const float4* __restrict__ wi0 = (const float4*)(w_ih + (0 * HH + t) * HH);
    const float4* __restrict__ wi1 = (const float4*)(w_ih + (1 * HH + t) * HH);
    const float4* __restrict__ wi2 = (const float4*)(w_ih + (2 * HH + t) * HH);
    const float4* __restrict__ wh0 = (const float4*)(w_hh + (0 * HH + t) * HH);
    const float4* __restrict__ wh1 = (const float4*)(w_hh + (1 * HH + t) * HH);
    const float4* __restrict__ wh2 = (const float4*)(w_hh + (2 * HH + t) * HH);

    #pragma unroll
    for (int k4 = 0; k4 < HH / 4; ++k4) {
        const float4 mv = *(const float4*)&ms[k4 * 4];
        const float4 hv = *(const float4*)&hs[k4 * 4];
        float4 a;
        a = wi0[k4]; gi0 += a.x * mv.x + a.y * mv.y + a.z * mv.z + a.w * mv.w;
        a = wi1[k4]; gi1 += a.x * mv.x + a.y * mv.y + a.z * mv.z + a.w * mv.w;
        a = wi2[k4]; gi2 += a.x * mv.x + a.y * mv.y + a.z * mv.z + a.w * mv.w;
        a = wh0[k4]; gh0 += a.x * hv.x + a.y * hv.y + a.z * hv.z + a.w * hv.w;
        a = wh1[k4]; gh1 += a.x * hv.x + a.y * hv.y + a.z * hv.z + a.w * hv.w;
        a = wh2[k4]; gh2 += a.x * hv.x + a.y * hv.y + a.z * hv.z + a.w * hv.w;
    }
    const float r = 1.f / (1.f + expf(-(gi0 + gh0)));
    const float z = 1.f / (1.f + expf(-(gi1 + gh1)));
    const float n = tanhf(gi2 + r * gh2);
    return (1.f - z) * n + z * hs[t];
}

// ---------------------------------------------------------------------------
// K1..K5: einsum on bf16 edge copy (L3-resident) + in-block GRU.
// grid = 288 blocks x 256 threads (4 waves); wave w streams i = 9w..9w+8.
// Per i: 8 uint4 (16B) chunks; k = 8*it + lane/8, l8 = lane&7. acc[8];
// 3-stage butterfly; lane (p,gq) holds k = 8p+gq -> LDS part[w][k].
// Then reduce 4 partials + GRU inline.
// ---------------------------------------------------------------------------
__global__ __launch_bounds__(256, 2) void step_bf16(
    const uint4* __restrict__ ebf,
    const float* __restrict__ nodes_in,
    const float* __restrict__ mask,
    const float* __restrict__ w_ih, const float* __restrict__ w_hh,
    const float* __restrict__ b_ih, const float* __restrict__ b_hh,
    float* __restrict__ nodes_out)
{
    const int tid  = threadIdx.x;
    const int lane = tid & 63;
    const int wv   = tid >> 6;
    const int bj = blockIdx.x;
    const int j  = bj % NN;
    const int b  = bj / NN;

    __shared__ float part[WAVES][HH];
    __shared__ float ms[HH];
    __shared__ float hs[HH];

    const int l8 = lane & 7;

    float acc[8];
    #pragma unroll
    for (int it = 0; it < 8; ++it) acc[it] = 0.f;

    for (int ii = 0; ii < IPW; ++ii) {
        const int i = wv * IPW + ii;
        const float* np_ = nodes_in + (b * NN + i) * HH + l8 * 8;
        const float4 v0 = *(const float4*)(np_);
        const float4 v1 = *(const float4*)(np_ + 4);
        const size_t blkElem = (size_t)((b * NN + i) * NN + j) * (HH * HH);
        const uint4* __restrict__ Wb = ebf + (blkElem >> 3);
        #pragma unroll
        for (int it = 0; it < 8; ++it) {
            const uint4 w = Wb[it * 64 + lane];
            acc[it] = fmaf(__uint_as_float(w.x << 16),          v0.x, acc[it]);
            acc[it] = fmaf(__uint_as_float(w.x & 0xffff0000u),  v0.y, acc[it]);
            acc[it] = fmaf(__uint_as_float(w.y << 16),          v0.z, acc[it]);
            acc[it] = fmaf(__uint_as_float(w.y & 0xffff0000u),  v0.w, acc[it]);
            acc[it] = fmaf(__uint_as_float(w.z << 16),          v1.x, acc[it]);
            acc[it] = fmaf(__uint_as_float(w.z & 0xffff0000u),  v1.y, acc[it]);
            acc[it] = fmaf(__uint_as_float(w.w << 16),          v1.z, acc[it]);
            acc[it] = fmaf(__uint_as_float(w.w & 0xffff0000u),  v1.w, acc[it]);
        }
    }

    #pragma unroll
    for (int m = 1; m < 8; m <<= 1) {
        #pragma unroll
        for (int it = 0; it < 8; ++it)
            acc[it] += __shfl_xor(acc[it], m, 64);
    }

    const int p  = lane & 7;
    const int gq = lane >> 3;
    float outv = acc[0];
    #pragma unroll
    for (int tt = 1; tt < 8; ++tt) outv = (p == tt) ? acc[tt] : outv;
    part[wv][8 * p + gq] = outv;

    __syncthreads();

    if (tid < HH) {
        const float m = part[0][tid] + part[1][tid] + part[2][tid] + part[3][tid];
        ms[tid] = m * INVN2;
        hs[tid] = nodes_in[bj * HH + tid];
    }
    __syncthreads();

    if (tid < HH) {
        const float o = gru_lane(ms, hs, tid, w_ih, w_hh, b_ih, b_hh);
        nodes_out[bj * HH + tid] = o * mask[bj];
    }
}

extern "C" void kernel_launch(void* const* d_in, const int* in_sizes, int n_in,
                              void* d_out, int out_size, void* d_ws, size_t ws_size,
                              hipStream_t stream) {
    const float* edge   = (const float*)d_in[0];
    const float* nodes0 = (const float*)d_in[1];
    const float* mask   = (const float*)d_in[2];
    const float* w_ih   = (const float*)d_in[3];
    const float* w_hh   = (const float*)d_in[4];
    const float* b_ih   = (const float*)d_in[5];
    const float* b_hh   = (const float*)d_in[6];
    float* out = (float*)d_out;

    float* ws = (float*)d_ws;
    const int nodes_elems = BB * NN * HH;          // 18432
    float* nodesA = ws;
    float* nodesB = ws + nodes_elems;
    float* ebf_f  = ws + 2 * nodes_elems;          // bf16 edge copy ~85 MB
    uint4* ebf4w  = (uint4*)ebf_f;
    const uint4* ebf4 = (const uint4*)ebf_f;

    // K0: pure streaming f32 -> bf16 conversion (memcpy-shaped)
    cvt_edge<<<1728, 256, 0, stream>>>(edge, ebf4w);

    // K1..K5: fused einsum+GRU steps on the bf16 copy
    step_bf16<<<NBJ, 256, 0, stream>>>(ebf4, nodes0, mask,
                                       w_ih, w_hh, b_ih, b_hh, nodesA);
    step_bf16<<<NBJ, 256, 0, stream>>>(ebf4, nodesA, mask,
                                       w_ih, w_hh, b_ih, b_hh, nodesB);
    step_bf16<<<NBJ, 256, 0, stream>>>(ebf4, nodesB, mask,
                                       w_ih, w_hh, b_ih, b_hh, nodesA);
    step_bf16<<<NBJ, 256, 0, stream>>>(ebf4, nodesA, mask,
                                       w_ih, w_hh, b_ih, b_hh, nodesB);
    step_bf16<<<NBJ, 256, 0, stream>>>(ebf4, nodesB, mask,
                                       w_ih, w_hh, b_ih, b_hh, out);
}

// Round 11
// 141.317 us; speedup vs baseline: 1.0568x; 1.0568x over previous
//
#include <hip/hip_runtime.h>
#include <hip/hip_bf16.h>

// MPNN: B=8, N=36, H=64, STEPS=5
// messages[b,j,k] = (1/N^2) * sum_{i,l} edge[b,i,j,k,l] * nodes[b,i,l]
// nodes = GRUCell(messages, nodes) * mask, repeated STEPS times.
//
// Structure (6 launches):
//  K1: einsum_f32_cvt, 3456x64: per (b,i,j) 64x64 block, lane loads 32B f32
//      (float8), 8 FMA into acc, packs to 8 bf16 via v_cvt_pk (compiler-fused
//      __float2bfloat16), stores 16B uint4. Butterfly reduce -> partial.
//  K2: gru_step, 288x64: reduce 12 partials + GRU -> nodes1.
//  K3..K6: step_bf16 fused einsum+GRU on the L3-resident bf16 copy
//      (measured ~9 us each, round 8).

#define BB 8
#define NN 36
#define HH 64
#define GG 12            // i-groups per (b,j) for K1
#define IPG (NN / GG)    // 3
#define WAVES 4          // waves/block in fused steps
#define IPW (NN / WAVES) // 9
#define NBJ (BB * NN)    // 288
#define INVN2 (1.0f / (float)(NN * NN))

typedef float f32x4 __attribute__((ext_vector_type(4)));

__device__ __forceinline__ unsigned pack_bf16_2(float lo, float hi) {
    // __float2bfloat16 is RNE; compiler fuses pairs into v_cvt_pk_bf16_f32
    __hip_bfloat16 a = __float2bfloat16(lo);
    __hip_bfloat16 b = __float2bfloat16(hi);
    unsigned ua = *reinterpret_cast<unsigned short*>(&a);
    unsigned ub = *reinterpret_cast<unsigned short*>(&b);
    return ua | (ub << 16);
}

// GRU cell for one node; lane t computes output dim t from LDS-staged
// message (ms) and hidden (hs) vectors. Rows t, t+64, t+128 of w_ih/w_hh.
__device__ __forceinline__ float gru_lane(
    const float* __restrict__ ms, const float* __restrict__ hs, int t,
    const float* __restrict__ w_ih, const float* __restrict__ w_hh,
    const float* __restrict__ b_ih, const float* __restrict__ b_hh)
{
    float gi0 = b_ih[t], gi1 = b_ih[HH + t], gi2 = b_ih[2 * HH + t];
    float gh0 = b_hh[t], gh1 = b_hh[HH + t], gh2 = b_hh[2 * HH + t];

    const float4* __restrict__ wi0 = (const float4*)(w_ih + (0 * HH + t) * HH);
    const float4* __restrict__ wi1 = (const float4*)(w_ih + (1 * HH + t) * HH);
    const float4* __restrict__ wi2 = (const float4*)(w_ih + (2 * HH + t) * HH);
    const float4* __restrict__ wh0 = (const float4*)(w_hh + (0 * HH + t) * HH);
    const float4* __restrict__ wh1 = (const float4*)(w_hh + (1 * HH + t) * HH);
    const float4* __restrict__ wh2 = (const float4*)(w_hh + (2 * HH + t) * HH);

    #pragma unroll
    for (int k4 = 0; k4 < HH / 4; ++k4) {
        const float4 mv = *(const float4*)&ms[k4 * 4];
        const float4 hv = *(const float4*)&hs[k4 * 4];
        float4 a;
        a = wi0[k4]; gi0 += a.x * mv.x + a.y * mv.y + a.z * mv.z + a.w * mv.w;
        a = wi1[k4]; gi1 += a.x * mv.x + a.y * mv.y + a.z * mv.z + a.w * mv.w;
        a = wi2[k4]; gi2 += a.x * mv.x + a.y * mv.y + a.z * mv.z + a.w * mv.w;
        a = wh0[k4]; gh0 += a.x * hv.x + a.y * hv.y + a.z * hv.z + a.w * hv.w;
        a = wh1[k4]; gh1 += a.x * hv.x + a.y * hv.y + a.z * hv.z + a.w * hv.w;
        a = wh2[k4]; gh2 += a.x * hv.x + a.y * hv.y + a.z * hv.z + a.w * hv.w;
    }
    const float r = 1.f / (1.f + expf(-(gi0 + gh0)));
    const float z = 1.f / (1.f + expf(-(gi1 + gh1)));
    const float n = tanhf(gi2 + r * gh2);
    return (1.f - z) * n + z * hs[t];
}

// ---------------------------------------------------------------------------
// K1: einsum on f32 edge + emit bf16 copy, wide accesses.
// grid = 3456 x 64. bid = (b*NN+j)*GG + g. Per (b,i,j) 64x64 f32 block:
// lane handles uint4-output o = it*64 + lane (it=0..7) covering f32 elems
// o*8..o*8+7: k = 8*it + (lane>>3), l = 8*(lane&7)+m. Loads 2x float4 (32B),
// 8 FMA vs node float8, packs 4x v_cvt_pk -> uint4 store (16B).
// Butterfly over low 3 lane bits sums l-blocks; lane (q=lane>>3,p=lane&7)
// writes k = 8*p + q from acc[p].
// ---------------------------------------------------------------------------
__global__ __launch_bounds__(64) void einsum_f32_cvt(
    const float* __restrict__ edge,
    const float* __restrict__ nodes,
    float* __restrict__ partial,
    uint4* __restrict__ ebf)
{
    const int lane = threadIdx.x;
    const int bid  = blockIdx.x;
    const int g = bid % GG;
    const int j = (bid / GG) % NN;
    const int b = bid / (GG * NN);

    const int p = lane & 7;    // l-block
    const int q = lane >> 3;   // k within octet

    float acc[8];
    #pragma unroll
    for (int it = 0; it < 8; ++it) acc[it] = 0.f;

    #pragma unroll
    for (int ii = 0; ii < IPG; ++ii) {
        const int i = g * IPG + ii;
        const float* np_ = nodes + (b * NN + i) * HH + p * 8;
        const float4 v0 = *(const float4*)(np_);
        const float4 v1 = *(const float4*)(np_ + 4);
        const size_t blkElem = (size_t)((b * NN + i) * NN + j) * (HH * HH);
        const float* __restrict__ Wf = edge + blkElem;
        uint4* __restrict__ Eb = ebf + (blkElem >> 3);
        #pragma unroll
        for (int it = 0; it < 8; ++it) {
            const int o = it * 64 + lane;
            const float4 a = *(const float4*)(Wf + (size_t)o * 8);
            const float4 c = *(const float4*)(Wf + (size_t)o * 8 + 4);
            acc[it] = fmaf(a.x, v0.x, acc[it]);
            acc[it] = fmaf(a.y, v0.y, acc[it]);
            acc[it] = fmaf(a.z, v0.z, acc[it]);
            acc[it] = fmaf(a.w, v0.w, acc[it]);
            acc[it] = fmaf(c.x, v1.x, acc[it]);
            acc[it] = fmaf(c.y, v1.y, acc[it]);
            acc[it] = fmaf(c.z, v1.z, acc[it]);
            acc[it] = fmaf(c.w, v1.w, acc[it]);
            uint4 pk;
            pk.x = pack_bf16_2(a.x, a.y);
            pk.y = pack_bf16_2(a.z, a.w);
            pk.z = pack_bf16_2(c.x, c.y);
            pk.w = pack_bf16_2(c.z, c.w);
            Eb[o] = pk;
        }
    }

    // sum across the 8 l-blocks (low 3 lane bits)
    #pragma unroll
    for (int m = 1; m < 8; m <<= 1) {
        #pragma unroll
        for (int it = 0; it < 8; ++it)
            acc[it] += __shfl_xor(acc[it], m, 64);
    }

    // lane (q,p) takes acc[p] -> k = 8*p + q
    float outv = acc[0];
    #pragma unroll
    for (int t = 1; t < 8; ++t) outv = (p == t) ? acc[t] : outv;

    partial[(size_t)bid * HH + (8 * p + q)] = outv;
}

// ---------------------------------------------------------------------------
// K2: reduce 12 partials + GRU -> nodes1. grid = 288 x 64.
// ---------------------------------------------------------------------------
__global__ __launch_bounds__(64) void gru_step(
    const float* __restrict__ partial,
    const float* __restrict__ nodes_in,
    const float* __restrict__ mask,
    const float* __restrict__ w_ih, const float* __restrict__ w_hh,
    const float* __restrict__ b_ih, const float* __restrict__ b_hh,
    float* __restrict__ nodes_out)
{
    const int t  = threadIdx.x;
    const int bj = blockIdx.x;

    float m = 0.f;
    #pragma unroll
    for (int g = 0; g < GG; ++g)
        m += partial[((size_t)bj * GG + g) * HH + t];

    __shared__ float ms[HH];
    __shared__ float hs[HH];
    ms[t] = m * INVN2;
    hs[t] = nodes_in[bj * HH + t];
    __syncthreads();

    const float o = gru_lane(ms, hs, t, w_ih, w_hh, b_ih, b_hh);
    nodes_out[bj * HH + t] = o * mask[bj];
}

// ---------------------------------------------------------------------------
// K3..K6: einsum on bf16 edge copy (L3-resident) + in-block GRU.
// grid = 288 x 256 (4 waves); wave w streams i = 9w..9w+8. Unchanged from
// round 8 (measured ~9 us/dispatch).
// ---------------------------------------------------------------------------
__global__ __launch_bounds__(256, 2) void step_bf16(
    const uint4* __restrict__ ebf,
    const float* __restrict__ nodes_in,
    const float* __restrict__ mask,
    const float* __restrict__ w_ih, const float* __restrict__ w_hh,
    const float* __restrict__ b_ih, const float* __restrict__ b_hh,
    float* __restrict__ nodes_out)
{
    const int tid  = threadIdx.x;
    const int lane = tid & 63;
    const int wv   = tid >> 6;
    const int bj = blockIdx.x;
    const int j  = bj % NN;
    const int b  = bj / NN;

    __shared__ float part[WAVES][HH];
    __shared__ float ms[HH];
    __shared__ float hs[HH];

    const int l8 = lane & 7;

    float acc[8];
    #pragma unroll
    for (int it = 0; it < 8; ++it) acc[it] = 0.f;

    for (int ii = 0; ii < IPW; ++ii) {
        const int i = wv * IPW + ii;
        const float* np_ = nodes_in + (b * NN + i) * HH + l8 * 8;
        const float4 v0 = *(const float4*)(np_);
        const float4 v1 = *(const float4*)(np_ + 4);
        const size_t blkElem = (size_t)((b * NN + i) * NN + j) * (HH * HH);
        const uint4* __restrict__ Wb = ebf + (blkElem >> 3);
        #pragma unroll
        for (int it = 0; it < 8; ++it) {
            const uint4 w = Wb[it * 64 + lane];
            acc[it] = fmaf(__uint_as_float(w.x << 16),          v0.x, acc[it]);
            acc[it] = fmaf(__uint_as_float(w.x & 0xffff0000u),  v0.y, acc[it]);
            acc[it] = fmaf(__uint_as_float(w.y << 16),          v0.z, acc[it]);
            acc[it] = fmaf(__uint_as_float(w.y & 0xffff0000u),  v0.w, acc[it]);
            acc[it] = fmaf(__uint_as_float(w.z << 16),          v1.x, acc[it]);
            acc[it] = fmaf(__uint_as_float(w.z & 0xffff0000u),  v1.y, acc[it]);
            acc[it] = fmaf(__uint_as_float(w.w << 16),          v1.z, acc[it]);
            acc[it] = fmaf(__uint_as_float(w.w & 0xffff0000u),  v1.w, acc[it]);
        }
    }

    #pragma unroll
    for (int m = 1; m < 8; m <<= 1) {
        #pragma unroll
        for (int it = 0; it < 8; ++it)
            acc[it] += __shfl_xor(acc[it], m, 64);
    }

    const int p  = lane & 7;
    const int gq = lane >> 3;
    float outv = acc[0];
    #pragma unroll
    for (int tt = 1; tt < 8; ++tt) outv = (p == tt) ? acc[tt] : outv;
    part[wv][8 * p + gq] = outv;

    __syncthreads();

    if (tid < HH) {
        const float m = part[0][tid] + part[1][tid] + part[2][tid] + part[3][tid];
        ms[tid] = m * INVN2;
        hs[tid] = nodes_in[bj * HH + tid];
    }
    __syncthreads();

    if (tid < HH) {
        const float o = gru_lane(ms, hs, tid, w_ih, w_hh, b_ih, b_hh);
        nodes_out[bj * HH + tid] = o * mask[bj];
    }
}

extern "C" void kernel_launch(void* const* d_in, const int* in_sizes, int n_in,
                              void* d_out, int out_size, void* d_ws, size_t ws_size,
                              hipStream_t stream) {
    const float* edge   = (const float*)d_in[0];
    const float* nodes0 = (const float*)d_in[1];
    const float* mask   = (const float*)d_in[2];
    const float* w_ih   = (const float*)d_in[3];
    const float* w_hh   = (const float*)d_in[4];
    const float* b_ih   = (const float*)d_in[5];
    const float* b_hh   = (const float*)d_in[6];
    float* out = (float*)d_out;

    float* ws = (float*)d_ws;
    const int nodes_elems   = BB * NN * HH;            // 18432
    const int partial_elems = NBJ * GG * HH;           // 221184
    float* nodesA  = ws;
    float* nodesB  = ws + nodes_elems;
    float* partial = ws + 2 * nodes_elems;
    float* ebf_f   = partial + partial_elems;          // bf16 edge copy ~85 MB
    uint4* ebf4w = (uint4*)ebf_f;
    const uint4* ebf4 = (const uint4*)ebf_f;

    // K1: messages1 -> partial (+ bf16 edge copy), wide loads/stores
    einsum_f32_cvt<<<NBJ * GG, 64, 0, stream>>>(edge, nodes0, partial, ebf4w);
    // K2: nodes1 = GRU(partial, nodes0)
    gru_step<<<NBJ, 64, 0, stream>>>(partial, nodes0, mask,
                                     w_ih, w_hh, b_ih, b_hh, nodesA);
    // K3..K6: fused bf16 steps
    step_bf16<<<NBJ, 256, 0, stream>>>(ebf4, nodesA, mask,
                                       w_ih, w_hh, b_ih, b_hh, nodesB);
    step_bf16<<<NBJ, 256, 0, stream>>>(ebf4, nodesB, mask,
                                       w_ih, w_hh, b_ih, b_hh, nodesA);
    step_bf16<<<NBJ, 256, 0, stream>>>(ebf4, nodesA, mask,
                                       w_ih, w_hh, b_ih, b_hh, nodesB);
    step_bf16<<<NBJ, 256, 0, stream>>>(ebf4, nodesB, mask,
                                       w_ih, w_hh, b_ih, b_hh, out);
}